// Round 8
// baseline (949.035 us; speedup 1.0000x reference)
//
#include <hip/hip_runtime.h>
#include <hip/hip_bf16.h>
#include <math.h>

// SlotAttention: B=64 N=4096 F=256 D=256 KVQ=256 H=4 S=8 DH=64 ITERS=3
// Round 8: K/V elimination. dots = q~ . xh  (q~ = M[h] @ sn, M = 0.125*WqH^T WkH),
// U = sum_j P * xh, updates = Wv @ (U + EPS*sum_j xh) * rs (folded into GRU).
// precvt writes Xh (row-major) + XhT (transposed); no projection GEMM at all.

using frag_ab = __attribute__((ext_vector_type(8))) short;   // 8 bf16
using f32x4  = __attribute__((ext_vector_type(4))) float;

__device__ __forceinline__ unsigned short f2bf(float f) {
  unsigned int x = __float_as_uint(f);
  x += 0x7fffu + ((x >> 16) & 1u);   // RNE
  return (unsigned short)(x >> 16);
}
__device__ __forceinline__ float bf2f(unsigned short u) {
  return __uint_as_float((unsigned int)u << 16);
}

// ---------------------------------------------------------------------------
// transpose gru weights + wv (WvT[f][gd] = wv[gd][f])
__global__ void k_transpose(const float* __restrict__ wih,
                            const float* __restrict__ whh,
                            const float* __restrict__ wv,
                            float* __restrict__ wihT, float* __restrict__ whhT,
                            float* __restrict__ wvT) {
  const int idx = blockIdx.x * 256 + threadIdx.x;
  if (idx < 768 * 256) {
    const int g = idx >> 8, k = idx & 255;
    wihT[k * 768 + g] = wih[idx];
  } else if (idx < 2 * 768 * 256) {
    const int j = idx - 768 * 256;
    const int g = j >> 8, k = j & 255;
    whhT[k * 768 + g] = whh[j];
  } else {
    const int j = idx - 2 * 768 * 256;
    const int c = j >> 8, k = j & 255;
    wvT[k * 256 + c] = wv[j];
  }
}

// ---------------------------------------------------------------------------
// M[h][D][f] = SCALE * sum_d wq[h*64+d][D] * wk[h*64+d][f]
__global__ __launch_bounds__(256) void k_mprep(const float* __restrict__ wq,
                                               const float* __restrict__ wk,
                                               float* __restrict__ M) {
  const int D = blockIdx.x, h = blockIdx.y, f = threadIdx.x;
  float acc = 0.f;
#pragma unroll 8
  for (int d = 0; d < 64; ++d)
    acc += wq[(h * 64 + d) * 256 + D] * wk[(h * 64 + d) * 256 + f];
  M[((h * 256) + D) * 256 + f] = acc * 0.125f;
}

// ---------------------------------------------------------------------------
// Pre-pass: dual-layout LN output. Block = 64 rows. Wave w does 16 rows.
// Lane l covers f = {l, l+64, l+128, l+192}. Writes Xh rows + LDS XT, then
// XhT[b][f][j] coalesced.
__global__ __launch_bounds__(256) void k_precvt(
    const float* __restrict__ xsrc, const float* __restrict__ lnw,
    const float* __restrict__ lnb, unsigned short* __restrict__ Xh,
    unsigned short* __restrict__ XhT) {
  __shared__ __align__(16) unsigned short XT[256 * 68];  // row stride 136B
  const int t = threadIdx.x;
  const int lane = t & 63, w = t >> 6;
  const long row0 = (long)blockIdx.x * 64;
  const long b = row0 >> 12;
  const long j0 = row0 & 4095;

  float w4[4], b4[4];
#pragma unroll
  for (int k = 0; k < 4; ++k) {
    w4[k] = lnw[k * 64 + lane];
    b4[k] = lnb[k * 64 + lane];
  }
  for (int rr = 0; rr < 16; ++rr) {
    const long row = row0 + w * 16 + rr;
    float x[4];
    float s = 0.f, ss = 0.f;
#pragma unroll
    for (int k = 0; k < 4; ++k) {
      x[k] = xsrc[row * 256 + k * 64 + lane];
      s += x[k];
      ss += x[k] * x[k];
    }
#pragma unroll
    for (int m = 1; m < 64; m <<= 1) {
      s += __shfl_xor(s, m);
      ss += __shfl_xor(ss, m);
    }
    const float mean = s * (1.f / 256.f);
    const float rstd = rsqrtf(ss * (1.f / 256.f) - mean * mean + 1e-5f);
#pragma unroll
    for (int k = 0; k < 4; ++k) {
      const unsigned short u = f2bf((x[k] - mean) * rstd * w4[k] + b4[k]);
      Xh[row * 256 + k * 64 + lane] = u;
      *(unsigned short*)((char*)XT + (k * 64 + lane) * 136 + (w * 16 + rr) * 2) = u;
    }
  }
  __syncthreads();
  // XhT store: 4 passes; thread (f = fp*64 + t>>2, jq = t&3) writes 32B.
#pragma unroll
  for (int fp = 0; fp < 4; ++fp) {
    const int f = fp * 64 + (t >> 2);
    const int jq = t & 3;
    uint2 v0 = *(const uint2*)((const char*)XT + f * 136 + jq * 32 + 0);
    uint2 v1 = *(const uint2*)((const char*)XT + f * 136 + jq * 32 + 8);
    uint2 v2 = *(const uint2*)((const char*)XT + f * 136 + jq * 32 + 16);
    uint2 v3 = *(const uint2*)((const char*)XT + f * 136 + jq * 32 + 24);
    unsigned short* dst = XhT + (b * 256 + f) * 4096 + j0 + jq * 16;
    *(uint4*)(dst) = make_uint4(v0.x, v0.y, v1.x, v1.y);
    *(uint4*)(dst + 8) = make_uint4(v2.x, v2.y, v3.x, v3.y);
  }
}

// ---------------------------------------------------------------------------
// svx[b][f] = sum_j xh[b][j][f]  (iteration-invariant, from XhT rows)
__global__ __launch_bounds__(256) void k_sv(const unsigned short* __restrict__ XhT,
                                            float* __restrict__ svx) {
  const int b = blockIdx.x >> 2, fq = blockIdx.x & 3;
  const int lane = threadIdx.x & 63, w = threadIdx.x >> 6;
  for (int rr = 0; rr < 16; ++rr) {
    const int f = fq * 64 + w * 16 + rr;
    const unsigned short* p = XhT + ((long)(b * 256 + f)) * 4096;
    float s = 0.f;
#pragma unroll
    for (int i = 0; i < 8; ++i) {
      const uint4 v = *(const uint4*)(p + i * 512 + lane * 8);
      s += bf2f((unsigned short)(v.x & 0xffff)) + bf2f((unsigned short)(v.x >> 16)) +
           bf2f((unsigned short)(v.y & 0xffff)) + bf2f((unsigned short)(v.y >> 16)) +
           bf2f((unsigned short)(v.z & 0xffff)) + bf2f((unsigned short)(v.z >> 16)) +
           bf2f((unsigned short)(v.w & 0xffff)) + bf2f((unsigned short)(v.w >> 16));
    }
#pragma unroll
    for (int m = 1; m < 64; m <<= 1) s += __shfl_xor(s, m);
    if (lane == 0) svx[b * 256 + f] = s;
  }
}

// ---------------------------------------------------------------------------
// LN(slots) + q~[b][ih][f] = sum_D sn[i][D] * M[h][D][f], written bf16
// PRE-SWIZZLED (byte ^ ((ih&7)<<4)) for linear DMA staging in k_att.
__global__ __launch_bounds__(256) void k_q(
    const float* __restrict__ slots, const float* __restrict__ lnw,
    const float* __restrict__ lnb, const float* __restrict__ M,
    unsigned short* __restrict__ qt) {
  __shared__ float sl[8 * 256];
  __shared__ float mstat[8], rstat[8];
  const int b = blockIdx.x, h = blockIdx.y, t = threadIdx.x;
#pragma unroll
  for (int i = 0; i < 8; ++i) sl[i * 256 + t] = slots[b * 2048 + i * 256 + t];
  __syncthreads();
  if (t < 8) {
    float s = 0.f, ss = 0.f;
    for (int k = 0; k < 256; ++k) {
      const float x = sl[t * 256 + k];
      s += x;
      ss += x * x;
    }
    const float m = s * (1.f / 256.f);
    mstat[t] = m;
    rstat[t] = rsqrtf(ss * (1.f / 256.f) - m * m + 1e-5f);
  }
  __syncthreads();
  const float w = lnw[t], bb = lnb[t];
#pragma unroll
  for (int i = 0; i < 8; ++i)
    sl[i * 256 + t] = (sl[i * 256 + t] - mstat[i]) * rstat[i] * w + bb;
  __syncthreads();
  float acc[8] = {};
  const float* Mh = M + h * 65536;
  for (int D = 0; D < 256; ++D) {
    const float m = Mh[D * 256 + t];
#pragma unroll
    for (int i = 0; i < 8; ++i) acc[i] += sl[i * 256 + D] * m;
  }
#pragma unroll
  for (int i = 0; i < 8; ++i) {
    const int ih = i * 4 + h;
    *(unsigned short*)((char*)qt + b * 16384 + ih * 512 +
                       ((2 * t) ^ ((ih & 7) << 4))) = f2bf(acc[i]);
  }
}

// ---------------------------------------------------------------------------
// Barrier-free attention core. Block (jt,b); wave owns 64 j (2 chunks of 32).
// QK^T: A = xh rows (global), B = q~ (LDS, swizzled). In-register inverted
// softmax over 32 ih. PU: A = P (wave LDS transpose), B = XhT rows (global);
// U[32 ih][256 f] accumulated in regs, reduced across waves in 4 LDS passes.
template <bool LAST>
__global__ __launch_bounds__(256) void k_att(
    const unsigned short* __restrict__ qt, const unsigned short* __restrict__ Xh,
    const unsigned short* __restrict__ XhT, float* __restrict__ upart,
    float* __restrict__ rowsum_part, float* __restrict__ attn_out) {
  __shared__ __align__(16) unsigned short Qs[32 * 256];  // 16KB swizzled q~
  __shared__ __align__(16) unsigned short Ps[4][1024];   // per-wave P
  __shared__ float ured[4][2048];                        // 32KB pass buffer
  __shared__ float wred[4][32];
  const int t = threadIdx.x;
  const int lane = t & 63, wid = t >> 6;
  const int li = lane & 15, kg = lane >> 4;
  const int b = blockIdx.y;
  const long j0 = (long)blockIdx.x * 256 + wid * 64;

  // stage q~ (bf16, already swizzled in global) via DMA
#pragma unroll
  for (int rnd = 0; rnd < 4; ++rnd)
    __builtin_amdgcn_global_load_lds(
        (const unsigned int*)((const char*)qt + b * 16384 + rnd * 4096 + t * 16),
        (unsigned int*)((char*)Qs + rnd * 4096 + t * 16), 16, 0, 0);
  __syncthreads();

  float rsum0 = 0.f, rsum1 = 0.f;
  f32x4 pv[2][16];
#pragma unroll
  for (int s = 0; s < 2; ++s)
#pragma unroll
    for (int ft = 0; ft < 16; ++ft) pv[s][ft] = (f32x4){0.f, 0.f, 0.f, 0.f};

  unsigned short* Pw = Ps[wid];

#pragma unroll
  for (int ch = 0; ch < 2; ++ch) {
    const long jc = j0 + ch * 32;
    // ---- QK^T: D[j][ih] ----
    f32x4 dacc[2][2];
    dacc[0][0] = (f32x4){0.f, 0.f, 0.f, 0.f};
    dacc[0][1] = (f32x4){0.f, 0.f, 0.f, 0.f};
    dacc[1][0] = (f32x4){0.f, 0.f, 0.f, 0.f};
    dacc[1][1] = (f32x4){0.f, 0.f, 0.f, 0.f};
#pragma unroll
    for (int jsub = 0; jsub < 2; ++jsub) {
      frag_ab kf[8];
      const unsigned short* kp =
          Xh + ((long)b * 4096 + jc + jsub * 16 + li) * 256 + kg * 8;
#pragma unroll
      for (int ks = 0; ks < 8; ++ks) kf[ks] = *(const frag_ab*)(kp + ks * 32);
#pragma unroll
      for (int g = 0; g < 2; ++g) {
        const char* qrow = (const char*)Qs + (g * 16 + li) * 512;
        const int swz = (li & 7) << 4;
#pragma unroll
        for (int ks = 0; ks < 8; ++ks) {
          const frag_ab qf = *(const frag_ab*)(qrow + ((ks * 64 + kg * 16) ^ swz));
          dacc[jsub][g] = __builtin_amdgcn_mfma_f32_16x16x32_bf16(
              kf[ks], qf, dacc[jsub][g], 0, 0, 0);
        }
      }
    }
    // ---- inverted softmax over 32 ih per j (scale folded into M) ----
    float p[2][2][4];
#pragma unroll
    for (int jsub = 0; jsub < 2; ++jsub) {
#pragma unroll
      for (int r = 0; r < 4; ++r) {
        const float d0 = dacc[jsub][0][r];
        const float d1 = dacc[jsub][1][r];
        float mx = fmaxf(d0, d1);
        mx = fmaxf(mx, __shfl_xor(mx, 1));
        mx = fmaxf(mx, __shfl_xor(mx, 2));
        mx = fmaxf(mx, __shfl_xor(mx, 4));
        mx = fmaxf(mx, __shfl_xor(mx, 8));
        float e0 = __expf(d0 - mx), e1 = __expf(d1 - mx);
        float sm = e0 + e1;
        sm += __shfl_xor(sm, 1);
        sm += __shfl_xor(sm, 2);
        sm += __shfl_xor(sm, 4);
        sm += __shfl_xor(sm, 8);
        const float inv = 1.f / sm;
        e0 *= inv;
        e1 *= inv;
        p[jsub][0][r] = e0;
        p[jsub][1][r] = e1;
        rsum0 += e0;
        rsum1 += e1;
        if (LAST) {
          float s0 = e0 + __shfl_xor(e0, 1);
          s0 += __shfl_xor(s0, 2);
          float s1 = e1 + __shfl_xor(e1, 1);
          s1 += __shfl_xor(s1, 2);
          if ((li & 3) == 0) {
            const long jg = jc + jsub * 16 + kg * 4 + r;
            attn_out[((long)b * 8 + (li >> 2)) * 4096 + jg] = s0 * 0.25f;
            attn_out[((long)b * 8 + 4 + (li >> 2)) * 4096 + jg] = s1 * 0.25f;
          }
        }
      }
    }
    // ---- P -> wave-private LDS (bf16, swizzled) ----
    asm volatile("s_waitcnt lgkmcnt(0)" ::: "memory");  // prev pa reads done
#pragma unroll
    for (int g = 0; g < 2; ++g) {
      const int ih = g * 16 + li;
      char* prow = (char*)Pw + ih * 64;
      const int swz = ((ih >> 2) & 3) << 4;
#pragma unroll
      for (int jsub = 0; jsub < 2; ++jsub)
#pragma unroll
        for (int rp = 0; rp < 2; ++rp) {
          const unsigned int pk =
              (unsigned)f2bf(p[jsub][g][2 * rp]) |
              ((unsigned)f2bf(p[jsub][g][2 * rp + 1]) << 16);
          const int jb = (jsub * 16 + kg * 4 + 2 * rp) * 2;
          *(unsigned int*)(prow + (jb ^ swz)) = pk;
        }
    }
    asm volatile("s_waitcnt lgkmcnt(0)" ::: "memory");  // P visible
    // ---- PU: U[ih][f] += P[ih][j] * xh[j][f] ----
    const frag_ab pa0 = *(const frag_ab*)(
        (const char*)Pw + li * 64 + ((kg * 16) ^ (((li >> 2) & 3) << 4)));
    const frag_ab pa1 = *(const frag_ab*)(
        (const char*)Pw + (16 + li) * 64 +
        ((kg * 16) ^ ((((16 + li) >> 2) & 3) << 4)));
#pragma unroll
    for (int ft = 0; ft < 16; ++ft) {
      const frag_ab vf = *(const frag_ab*)(
          XhT + ((long)b * 256 + ft * 16 + li) * 4096 + jc + kg * 8);
      pv[0][ft] = __builtin_amdgcn_mfma_f32_16x16x32_bf16(pa0, vf, pv[0][ft], 0, 0, 0);
      pv[1][ft] = __builtin_amdgcn_mfma_f32_16x16x32_bf16(pa1, vf, pv[1][ft], 0, 0, 0);
    }
  }

  // rowsum partials: reduce over kg, stash per wave
  rsum0 += __shfl_xor(rsum0, 16);
  rsum0 += __shfl_xor(rsum0, 32);
  rsum1 += __shfl_xor(rsum1, 16);
  rsum1 += __shfl_xor(rsum1, 32);
  if (lane < 16) {
    wred[wid][lane] = rsum0;
    wred[wid][16 + lane] = rsum1;
  }

  // U reduction across waves: 4 passes of 8 ih rows
  const long pb = (long)blockIdx.x * 64 + b;
#pragma unroll
  for (int p4 = 0; p4 < 4; ++p4) {
    __syncthreads();
    if ((kg >> 1) == (p4 & 1)) {
#pragma unroll
      for (int ft = 0; ft < 16; ++ft)
#pragma unroll
        for (int r = 0; r < 4; ++r)
          ured[wid][((kg & 1) * 4 + r) * 256 + ft * 16 + li] = pv[p4 >> 1][ft][r];
    }
    __syncthreads();
#pragma unroll
    for (int o = 0; o < 8; ++o) {
      const int idx = o * 256 + t;
      upart[(pb * 32 + p4 * 8 + o) * 256 + t] =
          ured[0][idx] + ured[1][idx] + ured[2][idx] + ured[3][idx];
    }
  }
  if (t < 32)
    rowsum_part[pb * 32 + t] = wred[0][t] + wred[1][t] + wred[2][t] + wred[3][t];
}

// ---------------------------------------------------------------------------
// GRU: U-reduce + EPS renorm in f-space, Wv projection, torch GRUCell.
template <bool LAST>
__global__ __launch_bounds__(256) void k_gru(
    const float* __restrict__ upart, const float* __restrict__ svx,
    const float* __restrict__ rowsum_part, const float* __restrict__ wihT,
    const float* __restrict__ whhT, const float* __restrict__ wvT,
    const float* __restrict__ bih, const float* __restrict__ bhh,
    float* __restrict__ slots, float* __restrict__ dout) {
  __shared__ float xu[32 * 256];   // X~ = (U + EPS*svx) * rs
  __shared__ float xl[8 * 256];    // updates (d-space)
  __shared__ float hl[8 * 256];
  __shared__ float rs[32];
  const int t = threadIdx.x;
  const int b = blockIdx.x;
  if (t < 32) {
    float s2 = 0.f;
#pragma unroll
    for (int p = 0; p < 16; ++p) s2 += rowsum_part[((long)(p * 64 + b)) * 32 + t];
    rs[t] = 1.f / (s2 + 4096.f * 1e-8f);
  }
  __syncthreads();
  const float svf = svx[b * 256 + t] * 1e-8f;
#pragma unroll 4
  for (int o = 0; o < 32; ++o) {
    float pp = 0.f;
#pragma unroll
    for (int p = 0; p < 16; ++p)
      pp += upart[(((long)(p * 64 + b)) * 32 + o) * 256 + t];
    xu[o * 256 + t] = (pp + svf) * rs[o];
  }
#pragma unroll
  for (int r = 0; r < 8; ++r) hl[r * 256 + t] = slots[b * 2048 + r * 256 + t];
  __syncthreads();
  // Wv projection: xl[i][gd=t] = sum_f WvT[f][t] * xu[i*4+h][f], h = t>>6
  {
    const int h = t >> 6;
    float a8[8] = {};
    for (int f = 0; f < 256; ++f) {
      const float wv = wvT[f * 256 + t];
#pragma unroll
      for (int i = 0; i < 8; ++i) a8[i] += wv * xu[(i * 4 + h) * 256 + f];
    }
#pragma unroll
    for (int i = 0; i < 8; ++i) xl[i * 256 + t] = a8[i];
  }
  __syncthreads();
  float air[8] = {}, aiz[8] = {}, ain[8] = {};
  float ahr[8] = {}, ahz[8] = {}, ahn[8] = {};
  for (int k = 0; k < 256; k += 4) {
    float wir[4], wiz[4], win_[4], whr[4], whz[4], whn[4];
#pragma unroll
    for (int u = 0; u < 4; ++u) {
      wir[u] = wihT[(k + u) * 768 + t];
      wiz[u] = wihT[(k + u) * 768 + 256 + t];
      win_[u] = wihT[(k + u) * 768 + 512 + t];
      whr[u] = whhT[(k + u) * 768 + t];
      whz[u] = whhT[(k + u) * 768 + 256 + t];
      whn[u] = whhT[(k + u) * 768 + 512 + t];
    }
#pragma unroll
    for (int r = 0; r < 8; ++r) {
      const float4 x4 = *(const float4*)(xl + r * 256 + k);
      const float4 h4 = *(const float4*)(hl + r * 256 + k);
      air[r] += x4.x * wir[0] + x4.y * wir[1] + x4.z * wir[2] + x4.w * wir[3];
      aiz[r] += x4.x * wiz[0] + x4.y * wiz[1] + x4.z * wiz[2] + x4.w * wiz[3];
      ain[r] += x4.x * win_[0] + x4.y * win_[1] + x4.z * win_[2] + x4.w * win_[3];
      ahr[r] += h4.x * whr[0] + h4.y * whr[1] + h4.z * whr[2] + h4.w * whr[3];
      ahz[r] += h4.x * whz[0] + h4.y * whz[1] + h4.z * whz[2] + h4.w * whz[3];
      ahn[r] += h4.x * whn[0] + h4.y * whn[1] + h4.z * whn[2] + h4.w * whn[3];
    }
  }
  const float bir = bih[t], biz = bih[256 + t], bin_ = bih[512 + t];
  const float bhr = bhh[t], bhz = bhh[256 + t], bhn = bhh[512 + t];
#pragma unroll
  for (int r = 0; r < 8; ++r) {
    const float rr = 1.f / (1.f + __expf(-(air[r] + bir + ahr[r] + bhr)));
    const float zz = 1.f / (1.f + __expf(-(aiz[r] + biz + ahz[r] + bhz)));
    const float nn2 = tanhf(ain[r] + bin_ + rr * (ahn[r] + bhn));
    const float hn = (1.f - zz) * nn2 + zz * hl[r * 256 + t];
    slots[b * 2048 + r * 256 + t] = hn;
    if (LAST) dout[b * 2048 + r * 256 + t] = hn;
  }
}

// ---------------------------------------------------------------------------
extern "C" void kernel_launch(void* const* d_in, const int* in_sizes, int n_in,
                              void* d_out, int out_size, void* d_ws,
                              size_t ws_size, hipStream_t stream) {
  const float* xin = (const float*)d_in[0];
  const float* cond = (const float*)d_in[1];
  const float* lnin_w = (const float*)d_in[2];
  const float* lnin_b = (const float*)d_in[3];
  const float* lns_w = (const float*)d_in[4];
  const float* lns_b = (const float*)d_in[5];
  const float* wq = (const float*)d_in[6];
  const float* wk = (const float*)d_in[7];
  const float* wv = (const float*)d_in[8];
  const float* gwih = (const float*)d_in[9];
  const float* gwhh = (const float*)d_in[10];
  const float* gbih = (const float*)d_in[11];
  const float* gbhh = (const float*)d_in[12];
  float* out = (float*)d_out;

  char* ws = (char*)d_ws;
  unsigned short* Xh = (unsigned short*)ws;   ws += 262144l * 256 * 2;      // 128MB
  unsigned short* XhT = (unsigned short*)ws;  ws += 64l * 256 * 4096 * 2;   // 128MB
  float* M = (float*)ws;                      ws += 4l * 256 * 256 * 4;     // 1MB
  unsigned short* qt = (unsigned short*)ws;   ws += 64l * 32 * 256 * 2;     // 1MB
  float* upart = (float*)ws;                  ws += 16l * 64 * 32 * 256 * 4;// 32MB
  float* svx = (float*)ws;                    ws += 64l * 256 * 4;
  float* rowsum_part = (float*)ws;            ws += 16l * 64 * 32 * 4;
  float* slots = (float*)ws;                  ws += 512l * 256 * 4;
  float* wihT = (float*)ws;                   ws += 256l * 768 * 4;
  float* whhT = (float*)ws;                   ws += 256l * 768 * 4;
  float* wvT = (float*)ws;                    ws += 256l * 256 * 4;
  // total ~293 MB

  hipMemcpyAsync(slots, cond, 512 * 256 * 4, hipMemcpyDeviceToDevice, stream);
  k_transpose<<<1792, 256, 0, stream>>>(gwih, gwhh, wv, wihT, whhT, wvT);
  k_mprep<<<dim3(256, 4), 256, 0, stream>>>(wq, wk, M);
  k_precvt<<<4096, 256, 0, stream>>>(xin, lnin_w, lnin_b, Xh, XhT);
  k_sv<<<256, 256, 0, stream>>>(XhT, svx);

  for (int it = 0; it < 3; ++it) {
    k_q<<<dim3(64, 4), 256, 0, stream>>>(slots, lns_w, lns_b, M, qt);
    if (it == 2)
      k_att<true><<<dim3(16, 64), 256, 0, stream>>>(qt, Xh, XhT, upart,
                                                    rowsum_part, out + 131072);
    else
      k_att<false><<<dim3(16, 64), 256, 0, stream>>>(qt, Xh, XhT, upart,
                                                     rowsum_part, out + 131072);
    if (it == 2)
      k_gru<true><<<64, 256, 0, stream>>>(upart, svx, rowsum_part, wihT, whhT,
                                          wvT, gbih, gbhh, slots, out);
    else
      k_gru<false><<<64, 256, 0, stream>>>(upart, svx, rowsum_part, wihT, whhT,
                                           wvT, gbih, gbhh, slots, out);
  }
}

// Round 9
// 757.978 us; speedup vs baseline: 1.2521x; 1.2521x over previous
//
#include <hip/hip_runtime.h>
#include <hip/hip_bf16.h>
#include <math.h>

// SlotAttention: B=64 N=4096 F=256 D=256 KVQ=256 H=4 S=8 DH=64 ITERS=3
// Round 9: r8 K/V-elimination kept; update path re-parallelized:
// k_upd (grid 4x64: U-reduce + EPS renorm + per-head Wv projection) and
// k_gru back to r7's grid(4,64) gate-split form.

using frag_ab = __attribute__((ext_vector_type(8))) short;   // 8 bf16
using f32x4  = __attribute__((ext_vector_type(4))) float;

__device__ __forceinline__ unsigned short f2bf(float f) {
  unsigned int x = __float_as_uint(f);
  x += 0x7fffu + ((x >> 16) & 1u);   // RNE
  return (unsigned short)(x >> 16);
}
__device__ __forceinline__ float bf2f(unsigned short u) {
  return __uint_as_float((unsigned int)u << 16);
}

// ---------------------------------------------------------------------------
// transpose gru weights + wv (WvT[f][gd] = wv[gd][f])
__global__ void k_transpose(const float* __restrict__ wih,
                            const float* __restrict__ whh,
                            const float* __restrict__ wv,
                            float* __restrict__ wihT, float* __restrict__ whhT,
                            float* __restrict__ wvT) {
  const int idx = blockIdx.x * 256 + threadIdx.x;
  if (idx < 768 * 256) {
    const int g = idx >> 8, k = idx & 255;
    wihT[k * 768 + g] = wih[idx];
  } else if (idx < 2 * 768 * 256) {
    const int j = idx - 768 * 256;
    const int g = j >> 8, k = j & 255;
    whhT[k * 768 + g] = whh[j];
  } else {
    const int j = idx - 2 * 768 * 256;
    const int c = j >> 8, k = j & 255;
    wvT[k * 256 + c] = wv[j];
  }
}

// ---------------------------------------------------------------------------
// M[h][D][f] = SCALE * sum_d wq[h*64+d][D] * wk[h*64+d][f]
__global__ __launch_bounds__(256) void k_mprep(const float* __restrict__ wq,
                                               const float* __restrict__ wk,
                                               float* __restrict__ M) {
  const int D = blockIdx.x, h = blockIdx.y, f = threadIdx.x;
  float acc = 0.f;
#pragma unroll 8
  for (int d = 0; d < 64; ++d)
    acc += wq[(h * 64 + d) * 256 + D] * wk[(h * 64 + d) * 256 + f];
  M[((h * 256) + D) * 256 + f] = acc * 0.125f;
}

// ---------------------------------------------------------------------------
// Pre-pass: dual-layout LN output. Block = 64 rows. Wave w does 16 rows.
__global__ __launch_bounds__(256) void k_precvt(
    const float* __restrict__ xsrc, const float* __restrict__ lnw,
    const float* __restrict__ lnb, unsigned short* __restrict__ Xh,
    unsigned short* __restrict__ XhT) {
  __shared__ __align__(16) unsigned short XT[256 * 68];  // row stride 136B
  const int t = threadIdx.x;
  const int lane = t & 63, w = t >> 6;
  const long row0 = (long)blockIdx.x * 64;
  const long b = row0 >> 12;
  const long j0 = row0 & 4095;

  float w4[4], b4[4];
#pragma unroll
  for (int k = 0; k < 4; ++k) {
    w4[k] = lnw[k * 64 + lane];
    b4[k] = lnb[k * 64 + lane];
  }
  for (int rr = 0; rr < 16; ++rr) {
    const long row = row0 + w * 16 + rr;
    float x[4];
    float s = 0.f, ss = 0.f;
#pragma unroll
    for (int k = 0; k < 4; ++k) {
      x[k] = xsrc[row * 256 + k * 64 + lane];
      s += x[k];
      ss += x[k] * x[k];
    }
#pragma unroll
    for (int m = 1; m < 64; m <<= 1) {
      s += __shfl_xor(s, m);
      ss += __shfl_xor(ss, m);
    }
    const float mean = s * (1.f / 256.f);
    const float rstd = rsqrtf(ss * (1.f / 256.f) - mean * mean + 1e-5f);
#pragma unroll
    for (int k = 0; k < 4; ++k) {
      const unsigned short u = f2bf((x[k] - mean) * rstd * w4[k] + b4[k]);
      Xh[row * 256 + k * 64 + lane] = u;
      *(unsigned short*)((char*)XT + (k * 64 + lane) * 136 + (w * 16 + rr) * 2) = u;
    }
  }
  __syncthreads();
#pragma unroll
  for (int fp = 0; fp < 4; ++fp) {
    const int f = fp * 64 + (t >> 2);
    const int jq = t & 3;
    uint2 v0 = *(const uint2*)((const char*)XT + f * 136 + jq * 32 + 0);
    uint2 v1 = *(const uint2*)((const char*)XT + f * 136 + jq * 32 + 8);
    uint2 v2 = *(const uint2*)((const char*)XT + f * 136 + jq * 32 + 16);
    uint2 v3 = *(const uint2*)((const char*)XT + f * 136 + jq * 32 + 24);
    unsigned short* dst = XhT + (b * 256 + f) * 4096 + j0 + jq * 16;
    *(uint4*)(dst) = make_uint4(v0.x, v0.y, v1.x, v1.y);
    *(uint4*)(dst + 8) = make_uint4(v2.x, v2.y, v3.x, v3.y);
  }
}

// ---------------------------------------------------------------------------
// svx[b][f] = sum_j xh[b][j][f]  (iteration-invariant)
__global__ __launch_bounds__(256) void k_sv(const unsigned short* __restrict__ XhT,
                                            float* __restrict__ svx) {
  const int b = blockIdx.x >> 2, fq = blockIdx.x & 3;
  const int lane = threadIdx.x & 63, w = threadIdx.x >> 6;
  for (int rr = 0; rr < 16; ++rr) {
    const int f = fq * 64 + w * 16 + rr;
    const unsigned short* p = XhT + ((long)(b * 256 + f)) * 4096;
    float s = 0.f;
#pragma unroll
    for (int i = 0; i < 8; ++i) {
      const uint4 v = *(const uint4*)(p + i * 512 + lane * 8);
      s += bf2f((unsigned short)(v.x & 0xffff)) + bf2f((unsigned short)(v.x >> 16)) +
           bf2f((unsigned short)(v.y & 0xffff)) + bf2f((unsigned short)(v.y >> 16)) +
           bf2f((unsigned short)(v.z & 0xffff)) + bf2f((unsigned short)(v.z >> 16)) +
           bf2f((unsigned short)(v.w & 0xffff)) + bf2f((unsigned short)(v.w >> 16));
    }
#pragma unroll
    for (int m = 1; m < 64; m <<= 1) s += __shfl_xor(s, m);
    if (lane == 0) svx[b * 256 + f] = s;
  }
}

// ---------------------------------------------------------------------------
// LN(slots) + q~[b][ih][f] = sum_D sn[i][D]*M[h][D][f], bf16 pre-swizzled.
__global__ __launch_bounds__(256) void k_q(
    const float* __restrict__ slots, const float* __restrict__ lnw,
    const float* __restrict__ lnb, const float* __restrict__ M,
    unsigned short* __restrict__ qt) {
  __shared__ float sl[8 * 256];
  __shared__ float mstat[8], rstat[8];
  const int b = blockIdx.x, h = blockIdx.y, t = threadIdx.x;
#pragma unroll
  for (int i = 0; i < 8; ++i) sl[i * 256 + t] = slots[b * 2048 + i * 256 + t];
  __syncthreads();
  if (t < 8) {
    float s = 0.f, ss = 0.f;
    for (int k = 0; k < 256; ++k) {
      const float x = sl[t * 256 + k];
      s += x;
      ss += x * x;
    }
    const float m = s * (1.f / 256.f);
    mstat[t] = m;
    rstat[t] = rsqrtf(ss * (1.f / 256.f) - m * m + 1e-5f);
  }
  __syncthreads();
  const float w = lnw[t], bb = lnb[t];
#pragma unroll
  for (int i = 0; i < 8; ++i)
    sl[i * 256 + t] = (sl[i * 256 + t] - mstat[i]) * rstat[i] * w + bb;
  __syncthreads();
  float acc[8] = {};
  const float* Mh = M + h * 65536;
  for (int D = 0; D < 256; ++D) {
    const float m = Mh[D * 256 + t];
#pragma unroll
    for (int i = 0; i < 8; ++i) acc[i] += sl[i * 256 + D] * m;
  }
#pragma unroll
  for (int i = 0; i < 8; ++i) {
    const int ih = i * 4 + h;
    *(unsigned short*)((char*)qt + b * 16384 + ih * 512 +
                       ((2 * t) ^ ((ih & 7) << 4))) = f2bf(acc[i]);
  }
}

// ---------------------------------------------------------------------------
// Barrier-free attention core (r8, unchanged).
template <bool LAST>
__global__ __launch_bounds__(256) void k_att(
    const unsigned short* __restrict__ qt, const unsigned short* __restrict__ Xh,
    const unsigned short* __restrict__ XhT, float* __restrict__ upart,
    float* __restrict__ rowsum_part, float* __restrict__ attn_out) {
  __shared__ __align__(16) unsigned short Qs[32 * 256];
  __shared__ __align__(16) unsigned short Ps[4][1024];
  __shared__ float ured[4][2048];
  __shared__ float wred[4][32];
  const int t = threadIdx.x;
  const int lane = t & 63, wid = t >> 6;
  const int li = lane & 15, kg = lane >> 4;
  const int b = blockIdx.y;
  const long j0 = (long)blockIdx.x * 256 + wid * 64;

#pragma unroll
  for (int rnd = 0; rnd < 4; ++rnd)
    __builtin_amdgcn_global_load_lds(
        (const unsigned int*)((const char*)qt + b * 16384 + rnd * 4096 + t * 16),
        (unsigned int*)((char*)Qs + rnd * 4096 + t * 16), 16, 0, 0);
  __syncthreads();

  float rsum0 = 0.f, rsum1 = 0.f;
  f32x4 pv[2][16];
#pragma unroll
  for (int s = 0; s < 2; ++s)
#pragma unroll
    for (int ft = 0; ft < 16; ++ft) pv[s][ft] = (f32x4){0.f, 0.f, 0.f, 0.f};

  unsigned short* Pw = Ps[wid];

#pragma unroll
  for (int ch = 0; ch < 2; ++ch) {
    const long jc = j0 + ch * 32;
    f32x4 dacc[2][2];
    dacc[0][0] = (f32x4){0.f, 0.f, 0.f, 0.f};
    dacc[0][1] = (f32x4){0.f, 0.f, 0.f, 0.f};
    dacc[1][0] = (f32x4){0.f, 0.f, 0.f, 0.f};
    dacc[1][1] = (f32x4){0.f, 0.f, 0.f, 0.f};
#pragma unroll
    for (int jsub = 0; jsub < 2; ++jsub) {
      frag_ab kf[8];
      const unsigned short* kp =
          Xh + ((long)b * 4096 + jc + jsub * 16 + li) * 256 + kg * 8;
#pragma unroll
      for (int ks = 0; ks < 8; ++ks) kf[ks] = *(const frag_ab*)(kp + ks * 32);
#pragma unroll
      for (int g = 0; g < 2; ++g) {
        const char* qrow = (const char*)Qs + (g * 16 + li) * 512;
        const int swz = (li & 7) << 4;
#pragma unroll
        for (int ks = 0; ks < 8; ++ks) {
          const frag_ab qf = *(const frag_ab*)(qrow + ((ks * 64 + kg * 16) ^ swz));
          dacc[jsub][g] = __builtin_amdgcn_mfma_f32_16x16x32_bf16(
              kf[ks], qf, dacc[jsub][g], 0, 0, 0);
        }
      }
    }
    float p[2][2][4];
#pragma unroll
    for (int jsub = 0; jsub < 2; ++jsub) {
#pragma unroll
      for (int r = 0; r < 4; ++r) {
        const float d0 = dacc[jsub][0][r];
        const float d1 = dacc[jsub][1][r];
        float mx = fmaxf(d0, d1);
        mx = fmaxf(mx, __shfl_xor(mx, 1));
        mx = fmaxf(mx, __shfl_xor(mx, 2));
        mx = fmaxf(mx, __shfl_xor(mx, 4));
        mx = fmaxf(mx, __shfl_xor(mx, 8));
        float e0 = __expf(d0 - mx), e1 = __expf(d1 - mx);
        float sm = e0 + e1;
        sm += __shfl_xor(sm, 1);
        sm += __shfl_xor(sm, 2);
        sm += __shfl_xor(sm, 4);
        sm += __shfl_xor(sm, 8);
        const float inv = 1.f / sm;
        e0 *= inv;
        e1 *= inv;
        p[jsub][0][r] = e0;
        p[jsub][1][r] = e1;
        rsum0 += e0;
        rsum1 += e1;
        if (LAST) {
          float s0 = e0 + __shfl_xor(e0, 1);
          s0 += __shfl_xor(s0, 2);
          float s1 = e1 + __shfl_xor(e1, 1);
          s1 += __shfl_xor(s1, 2);
          if ((li & 3) == 0) {
            const long jg = jc + jsub * 16 + kg * 4 + r;
            attn_out[((long)b * 8 + (li >> 2)) * 4096 + jg] = s0 * 0.25f;
            attn_out[((long)b * 8 + 4 + (li >> 2)) * 4096 + jg] = s1 * 0.25f;
          }
        }
      }
    }
    asm volatile("s_waitcnt lgkmcnt(0)" ::: "memory");
#pragma unroll
    for (int g = 0; g < 2; ++g) {
      const int ih = g * 16 + li;
      char* prow = (char*)Pw + ih * 64;
      const int swz = ((ih >> 2) & 3) << 4;
#pragma unroll
      for (int jsub = 0; jsub < 2; ++jsub)
#pragma unroll
        for (int rp = 0; rp < 2; ++rp) {
          const unsigned int pk =
              (unsigned)f2bf(p[jsub][g][2 * rp]) |
              ((unsigned)f2bf(p[jsub][g][2 * rp + 1]) << 16);
          const int jb = (jsub * 16 + kg * 4 + 2 * rp) * 2;
          *(unsigned int*)(prow + (jb ^ swz)) = pk;
        }
    }
    asm volatile("s_waitcnt lgkmcnt(0)" ::: "memory");
    const frag_ab pa0 = *(const frag_ab*)(
        (const char*)Pw + li * 64 + ((kg * 16) ^ (((li >> 2) & 3) << 4)));
    const frag_ab pa1 = *(const frag_ab*)(
        (const char*)Pw + (16 + li) * 64 +
        ((kg * 16) ^ ((((16 + li) >> 2) & 3) << 4)));
#pragma unroll
    for (int ft = 0; ft < 16; ++ft) {
      const frag_ab vf = *(const frag_ab*)(
          XhT + ((long)b * 256 + ft * 16 + li) * 4096 + jc + kg * 8);
      pv[0][ft] = __builtin_amdgcn_mfma_f32_16x16x32_bf16(pa0, vf, pv[0][ft], 0, 0, 0);
      pv[1][ft] = __builtin_amdgcn_mfma_f32_16x16x32_bf16(pa1, vf, pv[1][ft], 0, 0, 0);
    }
  }

  rsum0 += __shfl_xor(rsum0, 16);
  rsum0 += __shfl_xor(rsum0, 32);
  rsum1 += __shfl_xor(rsum1, 16);
  rsum1 += __shfl_xor(rsum1, 32);
  if (lane < 16) {
    wred[wid][lane] = rsum0;
    wred[wid][16 + lane] = rsum1;
  }

  const long pb = (long)blockIdx.x * 64 + b;
#pragma unroll
  for (int p4 = 0; p4 < 4; ++p4) {
    __syncthreads();
    if ((kg >> 1) == (p4 & 1)) {
#pragma unroll
      for (int ft = 0; ft < 16; ++ft)
#pragma unroll
        for (int r = 0; r < 4; ++r)
          ured[wid][((kg & 1) * 4 + r) * 256 + ft * 16 + li] = pv[p4 >> 1][ft][r];
    }
    __syncthreads();
#pragma unroll
    for (int o = 0; o < 8; ++o) {
      const int idx = o * 256 + t;
      upart[(pb * 32 + p4 * 8 + o) * 256 + t] =
          ured[0][idx] + ured[1][idx] + ured[2][idx] + ured[3][idx];
    }
  }
  if (t < 32)
    rowsum_part[pb * 32 + t] = wred[0][t] + wred[1][t] + wred[2][t] + wred[3][t];
}

// ---------------------------------------------------------------------------
// Update path: grid (4 h, 64 b). Reduce 16 upart partials for the 8 xu rows
// this head needs, apply EPS renorm, project through Wv -> updates (d-space).
__global__ __launch_bounds__(256) void k_upd(
    const float* __restrict__ upart, const float* __restrict__ svx,
    const float* __restrict__ rowsum_part, const float* __restrict__ wvT,
    float* __restrict__ updates) {
  __shared__ float xu[8][256];
  __shared__ float rs[32];
  const int t = threadIdx.x;
  const int h = blockIdx.x;
  const int b = blockIdx.y;
  if (t < 32) {
    float s2 = 0.f;
#pragma unroll
    for (int p = 0; p < 16; ++p) s2 += rowsum_part[((long)(p * 64 + b)) * 32 + t];
    rs[t] = 1.f / (s2 + 4096.f * 1e-8f);
  }
  __syncthreads();
  const float svf = svx[b * 256 + t] * 1e-8f;
#pragma unroll
  for (int o = 0; o < 8; ++o) {
    float pp = 0.f;
#pragma unroll
    for (int p = 0; p < 16; ++p)
      pp += upart[(((long)(p * 64 + b)) * 32 + o * 4 + h) * 256 + t];
    xu[o][t] = (pp + svf) * rs[o * 4 + h];
  }
  __syncthreads();
  // Wv projection: updates[b][i][h*64+dd] = sum_f wvT[f][h*64+dd] * xu[i][f]
  const int dd = t & 63, ig = t >> 6;
  float acc0 = 0.f, acc1 = 0.f;
  const int i0 = ig * 2, i1 = ig * 2 + 1;
  for (int f = 0; f < 256; f += 4) {
    float wv0 = wvT[(f + 0) * 256 + h * 64 + dd];
    float wv1 = wvT[(f + 1) * 256 + h * 64 + dd];
    float wv2 = wvT[(f + 2) * 256 + h * 64 + dd];
    float wv3 = wvT[(f + 3) * 256 + h * 64 + dd];
    const float4 x0 = *(const float4*)(&xu[i0][f]);
    const float4 x1 = *(const float4*)(&xu[i1][f]);
    acc0 += x0.x * wv0 + x0.y * wv1 + x0.z * wv2 + x0.w * wv3;
    acc1 += x1.x * wv0 + x1.y * wv1 + x1.z * wv2 + x1.w * wv3;
  }
  updates[((long)(b * 8 + i0)) * 256 + h * 64 + dd] = acc0;
  updates[((long)(b * 8 + i1)) * 256 + h * 64 + dd] = acc1;
}

// ---------------------------------------------------------------------------
// GRU cell, grid (4 s, 64 b): r7 structure, reading updates directly.
template <bool LAST>
__global__ __launch_bounds__(256) void k_gru(
    const float* __restrict__ updates, const float* __restrict__ wihT,
    const float* __restrict__ whhT, const float* __restrict__ bih,
    const float* __restrict__ bhh, float* __restrict__ slots,
    float* __restrict__ dout) {
  __shared__ float xl[8 * 256];
  __shared__ float hl[8 * 256];
  __shared__ float gbuf[3 * 1024];  // [gate][{gi,gh}][8 r][64 c]
  const int t = threadIdx.x;
  const int s = blockIdx.x;
  const int b = blockIdx.y;
#pragma unroll
  for (int r = 0; r < 8; ++r) {
    xl[r * 256 + t] = updates[((long)(b * 8 + r)) * 256 + t];
    hl[r * 256 + t] = slots[b * 2048 + r * 256 + t];
  }
  __syncthreads();
  const int gate = t >> 6;   // 0..3 (3 idle)
  const int c = t & 63;
  if (gate < 3) {
    const int gcol = gate * 256 + s * 64 + c;
    float ai[8] = {}, ah[8] = {};
    for (int k = 0; k < 256; k += 4) {
      float w_i[4], w_h[4];
#pragma unroll
      for (int u = 0; u < 4; ++u) {
        w_i[u] = wihT[(k + u) * 768 + gcol];
        w_h[u] = whhT[(k + u) * 768 + gcol];
      }
#pragma unroll
      for (int r = 0; r < 8; ++r) {
        const float4 x4 = *(const float4*)(xl + r * 256 + k);
        const float4 h4 = *(const float4*)(hl + r * 256 + k);
        ai[r] += x4.x * w_i[0] + x4.y * w_i[1] + x4.z * w_i[2] + x4.w * w_i[3];
        ah[r] += h4.x * w_h[0] + h4.y * w_h[1] + h4.z * w_h[2] + h4.w * w_h[3];
      }
    }
    const float bi = bih[gcol], bh = bhh[gcol];
#pragma unroll
    for (int r = 0; r < 8; ++r) {
      gbuf[gate * 1024 + r * 64 + c] = ai[r] + bi;
      gbuf[gate * 1024 + 512 + r * 64 + c] = ah[r] + bh;
    }
  }
  __syncthreads();
#pragma unroll
  for (int o = 0; o < 2; ++o) {
    const int idx = o * 256 + t;
    const int r = idx >> 6, cc = idx & 63;
    const float gi_r = gbuf[r * 64 + cc], gh_r = gbuf[512 + r * 64 + cc];
    const float gi_z = gbuf[1024 + r * 64 + cc], gh_z = gbuf[1536 + r * 64 + cc];
    const float gi_n = gbuf[2048 + r * 64 + cc], gh_n = gbuf[2560 + r * 64 + cc];
    const float rr = 1.f / (1.f + __expf(-(gi_r + gh_r)));
    const float zz = 1.f / (1.f + __expf(-(gi_z + gh_z)));
    const float nn = tanhf(gi_n + rr * gh_n);
    const float h_old = hl[r * 256 + s * 64 + cc];
    const float hn = (1.f - zz) * nn + zz * h_old;
    slots[b * 2048 + r * 256 + s * 64 + cc] = hn;
    if (LAST) dout[b * 2048 + r * 256 + s * 64 + cc] = hn;
  }
}

// ---------------------------------------------------------------------------
extern "C" void kernel_launch(void* const* d_in, const int* in_sizes, int n_in,
                              void* d_out, int out_size, void* d_ws,
                              size_t ws_size, hipStream_t stream) {
  const float* xin = (const float*)d_in[0];
  const float* cond = (const float*)d_in[1];
  const float* lnin_w = (const float*)d_in[2];
  const float* lnin_b = (const float*)d_in[3];
  const float* lns_w = (const float*)d_in[4];
  const float* lns_b = (const float*)d_in[5];
  const float* wq = (const float*)d_in[6];
  const float* wk = (const float*)d_in[7];
  const float* wv = (const float*)d_in[8];
  const float* gwih = (const float*)d_in[9];
  const float* gwhh = (const float*)d_in[10];
  const float* gbih = (const float*)d_in[11];
  const float* gbhh = (const float*)d_in[12];
  float* out = (float*)d_out;

  char* ws = (char*)d_ws;
  unsigned short* Xh = (unsigned short*)ws;   ws += 262144l * 256 * 2;      // 128MB
  unsigned short* XhT = (unsigned short*)ws;  ws += 64l * 256 * 4096 * 2;   // 128MB
  float* M = (float*)ws;                      ws += 4l * 256 * 256 * 4;     // 1MB
  unsigned short* qt = (unsigned short*)ws;   ws += 64l * 32 * 256 * 2;     // 1MB
  float* upart = (float*)ws;                  ws += 16l * 64 * 32 * 256 * 4;// 32MB
  float* svx = (float*)ws;                    ws += 64l * 256 * 4;
  float* rowsum_part = (float*)ws;            ws += 16l * 64 * 32 * 4;
  float* updates = (float*)ws;                ws += 512l * 256 * 4;
  float* slots = (float*)ws;                  ws += 512l * 256 * 4;
  float* wihT = (float*)ws;                   ws += 256l * 768 * 4;
  float* whhT = (float*)ws;                   ws += 256l * 768 * 4;
  float* wvT = (float*)ws;                    ws += 256l * 256 * 4;
  // total ~294 MB

  hipMemcpyAsync(slots, cond, 512 * 256 * 4, hipMemcpyDeviceToDevice, stream);
  k_transpose<<<1792, 256, 0, stream>>>(gwih, gwhh, wv, wihT, whhT, wvT);
  k_mprep<<<dim3(256, 4), 256, 0, stream>>>(wq, wk, M);
  k_precvt<<<4096, 256, 0, stream>>>(xin, lnin_w, lnin_b, Xh, XhT);
  k_sv<<<256, 256, 0, stream>>>(XhT, svx);

  for (int it = 0; it < 3; ++it) {
    k_q<<<dim3(64, 4), 256, 0, stream>>>(slots, lns_w, lns_b, M, qt);
    if (it == 2)
      k_att<true><<<dim3(16, 64), 256, 0, stream>>>(qt, Xh, XhT, upart,
                                                    rowsum_part, out + 131072);
    else
      k_att<false><<<dim3(16, 64), 256, 0, stream>>>(qt, Xh, XhT, upart,
                                                     rowsum_part, out + 131072);
    k_upd<<<dim3(4, 64), 256, 0, stream>>>(upart, svx, rowsum_part, wvT, updates);
    if (it == 2)
      k_gru<true><<<dim3(4, 64), 256, 0, stream>>>(updates, wihT, whhT, gbih,
                                                   gbhh, slots, out);
    else
      k_gru<false><<<dim3(4, 64), 256, 0, stream>>>(updates, wihT, whhT, gbih,
                                                    gbhh, slots, out);
  }
}